// Round 1
// baseline (269143.604 us; speedup 1.0000x reference)
//
#include <hip/hip_runtime.h>
#include <stdint.h>

#define TDEC 800
#define NBATCH 64
#define TE 512
#define ED 512
#define NMEL 80
#define PRE 256
#define AR 1024
#define AD 128

typedef unsigned short u16;
typedef __bf16 bf16x8 __attribute__((ext_vector_type(8)));
typedef float f32x4 __attribute__((ext_vector_type(4)));

struct Args {
  // inputs
  const float *mem, *dec_in; const int *mlen;
  const float *W1, *b1, *W2, *b2;
  const float *Wi_a, *Wh_a, *bi_a, *bh_a;
  const float *Wq, *Wm, *v_in, *Wloc, *Wld;
  const float *Wi_d, *Wh_d, *bi_d, *bh_d;
  const float *Wp, *bp, *Wg, *bg;
  // control / state
  int *cnt, *gen, *pw_flag, *done; float *expsum;
  u16 *ah_bf, *hc; float *ac, *dc, *aw, *awc;
  // staged data
  u16 *x_all, *pmem_bf, *mem_bf, *hid_bf;
  u16 *WaSwz, *WdSwz, *WqSwz, *WpgSwz, *U2Swz;
  float *bias_a, *bias_d, *bpg;
  float *pq, *exp_e; u16 *loc_bf; float *gates_part;
  // outputs
  float *out_mel, *out_gate, *out_align;
};

__device__ __forceinline__ float b2f(u16 h){ return __uint_as_float(((uint32_t)h) << 16); }
__device__ __forceinline__ u16 f2b(float f){
  uint32_t u = __float_as_uint(f);
  uint32_t r = (u + 0x7fffu + ((u >> 16) & 1u)) >> 16;
  return (u16)r;
}
__device__ __forceinline__ float sigm(float x){ return 1.f / (1.f + __expf(-x)); }
__device__ __forceinline__ float tanh_(float x){ float e = __expf(2.f*x); return 1.f - 2.f/(e + 1.f); }

__device__ __forceinline__ f32x4 mfma16(bf16x8 a, bf16x8 b, f32x4 c){
  return __builtin_amdgcn_mfma_f32_16x16x32_bf16(a, b, c, 0, 0, 0);
}
__device__ __forceinline__ bf16x8 ldf(const u16* p){ return *(const bf16x8*)p; }

// ---------------- grid barrier (agent scope, sense via generation counter) ----
__device__ void gbar(const Args& A, int target){
  __syncthreads();
  if (threadIdx.x == 0){
    int old = __hip_atomic_fetch_add(A.cnt, 1, __ATOMIC_ACQ_REL, __HIP_MEMORY_SCOPE_AGENT);
    if (old == 255){
      __hip_atomic_store(A.cnt, 0, __ATOMIC_RELAXED, __HIP_MEMORY_SCOPE_AGENT);
      __hip_atomic_fetch_add(A.gen, 1, __ATOMIC_RELEASE, __HIP_MEMORY_SCOPE_AGENT);
    } else {
      while (__hip_atomic_load(A.gen, __ATOMIC_ACQUIRE, __HIP_MEMORY_SCOPE_AGENT) < target)
        __builtin_amdgcn_s_sleep(1);
    }
  }
  __syncthreads();
}

// ---------------- Phase 1: gate GEMM (split-K x4) + fused LSTM pointwise ------
// which=0: attn LSTM (K=1792), computed for step t.  which=1: dec LSTM (K=2560), step t-1.
// Columns are gate-interleaved: n = 4*j + gate, j = hidden unit.
__device__ void gemm_unit(const Args& A, int which, int t, int blk, int tid){
  const int pc = t & 1, pp = (t + 1) & 1;
  const int nc = blk >> 2, kq = blk & 3;     // nc: 64-col chunk, kq: K quarter
  const int NKT = which ? 80 : 56;           // total k-tiles (32 wide)
  const int ktn = NKT >> 2;
  const int kt0 = kq * ktn;
  const u16* Bsw = which ? A.WdSwz : A.WaSwz;
  const int wave = tid >> 6, lane = tid & 63;
  const int mrow = (wave << 4) + (lane & 15);
  const int kg = (lane >> 4) << 3;
  const u16* ah_p  = A.ah_bf + (size_t)pp * NBATCH * AR;
  const u16* hc_pp = A.hc + (size_t)pp * NBATCH * 1536;
  const u16* hc_pc = A.hc + (size_t)pc * NBATCH * 1536;
  f32x4 acc0 = {0.f,0.f,0.f,0.f}, acc1 = acc0, acc2 = acc0, acc3 = acc0;
  const size_t ntS = (size_t)NKT * 512;      // u16 elems per n-tile in swizzled B
  for (int kk = 0; kk < ktn; ++kk){
    int kt = kt0 + kk;
    int k = (kt << 5) + kg;
    const u16* ap;
    if (which == 0){
      if (k < 256)       ap = A.x_all + ((size_t)t * NBATCH + mrow) * PRE + k;
      else if (k < 768)  ap = hc_pp + (size_t)mrow * 1536 + 1024 + (k - 256);
      else               ap = ah_p + (size_t)mrow * AR + (k - 768);
    } else {
      if (k < 1024)      ap = ah_p + (size_t)mrow * AR + k;
      else if (k < 1536) ap = hc_pp + (size_t)mrow * 1536 + 1024 + (k - 1024);
      else               ap = hc_pc + (size_t)mrow * 1536 + (k - 1536);
    }
    bf16x8 af = ldf(ap);
    const u16* bb = Bsw + (((size_t)(nc * 4) * NKT + kt) * 64 + lane) * 8;
    acc0 = mfma16(af, ldf(bb),           acc0);
    acc1 = mfma16(af, ldf(bb + ntS),     acc1);
    acc2 = mfma16(af, ldf(bb + 2 * ntS), acc2);
    acc3 = mfma16(af, ldf(bb + 3 * ntS), acc3);
  }
  float* gp = A.gates_part + (size_t)(which * 4 + kq) * NBATCH * 4096;
  int r0 = (wave << 4) + ((lane >> 4) << 2);
  int c0 = (nc << 6) + (lane & 15);
  #pragma unroll
  for (int r = 0; r < 4; ++r){
    gp[(size_t)(r0 + r) * 4096 + c0     ] = acc0[r];
    gp[(size_t)(r0 + r) * 4096 + c0 + 16] = acc1[r];
    gp[(size_t)(r0 + r) * 4096 + c0 + 32] = acc2[r];
    gp[(size_t)(r0 + r) * 4096 + c0 + 48] = acc3[r];
  }
  __syncthreads();          // drains vmem stores of all waves
  __shared__ int s_last;
  if (tid == 0){
    int old = __hip_atomic_fetch_add(&A.pw_flag[which * 64 + nc], 1,
                                     __ATOMIC_ACQ_REL, __HIP_MEMORY_SCOPE_AGENT);
    s_last = (old == 3) ? 1 : 0;
  }
  __syncthreads();
  if (s_last){
    // LSTM pointwise for j in [nc*16, nc*16+16), all 64 batches
    const float* bias = which ? A.bias_d : A.bias_a;
    float* cst = which ? A.dc : A.ac;
    u16* hout = which ? (A.hc + (size_t)pp * NBATCH * 1536)
                      : (A.ah_bf + (size_t)pc * NBATCH * AR);
    int hstride = which ? 1536 : 1024;
    const float* g0 = A.gates_part + (size_t)which * 4 * NBATCH * 4096;
    for (int cell = tid; cell < 1024; cell += 256){
      int b = cell >> 4, jj = cell & 15;
      int col = (nc << 6) + (jj << 2);
      size_t base = (size_t)b * 4096 + col;
      float gi = 0.f, gf = 0.f, gg = 0.f, go = 0.f;
      #pragma unroll
      for (int q = 0; q < 4; ++q){
        const float* gq = g0 + (size_t)q * NBATCH * 4096 + base;
        gi += gq[0]; gf += gq[1]; gg += gq[2]; go += gq[3];
      }
      gi += bias[col]; gf += bias[col + 1]; gg += bias[col + 2]; go += bias[col + 3];
      int j = (nc << 4) + jj;
      size_t ci = (size_t)b * AR + j;
      float cold = cst[ci];
      float cn = sigm(gf) * cold + sigm(gi) * tanh_(gg);
      cst[ci] = cn;
      float h = sigm(go) * tanh_(cn);
      hout[(size_t)b * hstride + j] = f2b(h);
    }
  }
}

// ---------------- Phase 2a: fused conv31(aw,awc) x Wld -> loc (K=64 MFMA GEMM)
__device__ void loc_unit(const Args& A, int t, int blk, int tid){
  __shared__ u16 X[256 * 72];                // im2col, row stride 72 (16B aligned)
  int b = blk & 63, half = blk >> 6;
  for (int idx = tid; idx < 256 * 64; idx += 256){
    int tt = idx >> 6, ck = idx & 63;
    int c = ck >> 5, kk = ck & 31;
    float val = 0.f;
    if (kk < 31){
      int tg = (half << 8) + tt - 15 + kk;
      if (tg >= 0 && tg < TE) val = (c ? A.awc : A.aw)[(size_t)b * TE + tg];
    }
    X[tt * 72 + ck] = f2b(val);
  }
  __syncthreads();
  int wave = tid >> 6, lane = tid & 63;
  bf16x8 bf[2][8];
  #pragma unroll
  for (int kt = 0; kt < 2; ++kt)
    #pragma unroll
    for (int nt = 0; nt < 8; ++nt)
      bf[kt][nt] = ldf(A.U2Swz + (((nt * 2 + kt) << 6) + lane) * 8);
  for (int mt = wave; mt < 16; mt += 4){
    f32x4 acc[8];
    #pragma unroll
    for (int nt = 0; nt < 8; ++nt) acc[nt] = f32x4{0.f,0.f,0.f,0.f};
    #pragma unroll
    for (int kt = 0; kt < 2; ++kt){
      bf16x8 af = *(const bf16x8*)&X[((mt << 4) + (lane & 15)) * 72 + (kt << 5) + ((lane >> 4) << 3)];
      #pragma unroll
      for (int nt = 0; nt < 8; ++nt) acc[nt] = mfma16(af, bf[kt][nt], acc[nt]);
    }
    int tg = (half << 8) + (mt << 4) + ((lane >> 4) << 2);
    #pragma unroll
    for (int nt = 0; nt < 8; ++nt){
      int d = (nt << 4) + (lane & 15);
      u16* op = A.loc_bf + ((size_t)b * TE) * AD + d;
      #pragma unroll
      for (int r = 0; r < 4; ++r) op[(size_t)(tg + r) * AD] = f2b(acc[nt][r]);
    }
  }
}

// ---------------- Phase 2b: pq = ah @ Wq^T (8 blocks, one 16-col slice each) --
__device__ void pq_unit(const Args& A, int t, int s, int tid){
  int pc = t & 1;
  int wave = tid >> 6, lane = tid & 63;
  int m = (wave << 4) + (lane & 15), kg = (lane >> 4) << 3;
  const u16* arow = A.ah_bf + (size_t)pc * NBATCH * AR + (size_t)m * AR + kg;
  f32x4 acc = {0.f,0.f,0.f,0.f};
  for (int kt = 0; kt < 32; ++kt){
    bf16x8 af = ldf(arow + (kt << 5));
    bf16x8 bb = ldf(A.WqSwz + ((((size_t)s * 32 + kt) << 6) + lane) * 8);
    acc = mfma16(af, bb, acc);
  }
  int r0 = (wave << 4) + ((lane >> 4) << 2);
  int d = (s << 4) + (lane & 15);
  #pragma unroll
  for (int r = 0; r < 4; ++r) A.pq[(size_t)(r0 + r) * AD + d] = acc[r];
}

// ---------------- Phase 2c: mel/gate projection of step t-1 (split-K x2) -----
__device__ void proj_unit(const Args& A, int t, int u, int tid){
  int pp = (t + 1) & 1;                      // parity of t-1
  int kh = u / 6, ns = u % 6;
  int wave = tid >> 6, lane = tid & 63;
  int m = (wave << 4) + (lane & 15), kg = (lane >> 4) << 3;
  const u16* arow = A.hc + (size_t)pp * NBATCH * 1536 + (size_t)m * 1536 + kg;
  f32x4 acc = {0.f,0.f,0.f,0.f};
  for (int kk = 0; kk < 24; ++kk){
    int kt = kh * 24 + kk;
    bf16x8 af = ldf(arow + (kt << 5));
    bf16x8 bb = ldf(A.WpgSwz + ((((size_t)ns * 48 + kt) << 6) + lane) * 8);
    acc = mfma16(af, bb, acc);
  }
  int r0 = (wave << 4) + ((lane >> 4) << 2);
  int n = (ns << 4) + (lane & 15);
  #pragma unroll
  for (int r = 0; r < 4; ++r){
    int b = r0 + r;
    float val = acc[r];
    if (kh == 0) val += A.bpg[n];
    if (n < 80)        atomicAdd(&A.out_mel[((size_t)b * TDEC + (t - 1)) * NMEL + n], val);
    else if (n == 80)  atomicAdd(&A.out_gate[(size_t)b * TDEC + (t - 1)], val);
  }
}

// ---------------- Phase 3: e=tanh(pq+loc+pmem)@v, softmax, ctx=aw@mem --------
__device__ void attn_unit(const Args& A, int t, int blk, int tid){
  __shared__ float s_pq[128], s_v[128], s_red[4], s_ctx[512];
  int b = blk & 63, c = blk >> 6;
  if (tid < 128){ s_pq[tid] = A.pq[(size_t)b * AD + tid]; s_v[tid] = A.v_in[tid]; }
  __syncthreads();
  int mlen = A.mlen[b];
  int tt = tid >> 1, h = tid & 1;
  int tg = (c << 7) + tt;
  const u16* lrow = A.loc_bf  + ((size_t)b * TE + tg) * AD + (h << 6);
  const u16* prow = A.pmem_bf + ((size_t)b * TE + tg) * AD + (h << 6);
  float s = 0.f;
  for (int d0 = 0; d0 < 64; d0 += 8){
    bf16x8 lv = ldf(lrow + d0);
    bf16x8 pv = ldf(prow + d0);
    #pragma unroll
    for (int j = 0; j < 8; ++j){
      int d = (h << 6) + d0 + j;
      float arg = s_pq[d] + (float)lv[j] + (float)pv[j];
      s += tanh_(arg) * s_v[d];
    }
  }
  s += __shfl_xor(s, 1);
  float ex = 0.f;
  if (h == 0){
    if (tg < mlen) ex = __expf(s);
    A.exp_e[(size_t)b * TE + tg] = ex;
  }
  float r = ex;
  #pragma unroll
  for (int o = 32; o >= 1; o >>= 1) r += __shfl_xor(r, o);
  int wave = tid >> 6, lane = tid & 63;
  if (lane == 0) s_red[wave] = r;
  __syncthreads();
  if (tid == 0){
    float tot = s_red[0] + s_red[1] + s_red[2] + s_red[3];
    atomicAdd(&A.expsum[b], tot);
    __hip_atomic_fetch_add(&A.done[b], 1, __ATOMIC_ACQ_REL, __HIP_MEMORY_SCOPE_AGENT);
    while (__hip_atomic_load(&A.done[b], __ATOMIC_ACQUIRE, __HIP_MEMORY_SCOPE_AGENT) < 4)
      __builtin_amdgcn_s_sleep(1);
  }
  __syncthreads();
  float es = __hip_atomic_load(&A.expsum[b], __ATOMIC_ACQUIRE, __HIP_MEMORY_SCOPE_AGENT);
  float inv = 1.f / es;
  // ctx over d-chunk c*128, K split by wave over 4 t-quarters
  int dd = tid & 63, q = tid >> 6;
  int d = (c << 7) + (dd << 1);
  const u16* mb = A.mem_bf + ((size_t)b * TE) * ED + d;
  const float* ee = A.exp_e + (size_t)b * TE + (q << 7);
  float a0 = 0.f, a1 = 0.f;
  for (int i = 0; i < 128; ++i){
    float awt = ee[i];
    uint32_t uu = *(const uint32_t*)(mb + (size_t)((q << 7) + i) * ED);
    a0 += awt * b2f((u16)(uu & 0xffff));
    a1 += awt * b2f((u16)(uu >> 16));
  }
  s_ctx[q * 128 + (dd << 1)] = a0;
  s_ctx[q * 128 + (dd << 1) + 1] = a1;
  __syncthreads();
  if (tid < 128){
    float sum = (s_ctx[tid] + s_ctx[128 + tid] + s_ctx[256 + tid] + s_ctx[384 + tid]) * inv;
    int pc = t & 1;
    A.hc[(size_t)pc * NBATCH * 1536 + (size_t)b * 1536 + 1024 + (c << 7) + tid] = f2b(sum);
  }
  if (c == 0){
    for (int i = tid; i < TE; i += 256){
      float awt = A.exp_e[(size_t)b * TE + i] * inv;
      A.aw[(size_t)b * TE + i] = awt;
      A.awc[(size_t)b * TE + i] += awt;
      A.out_align[((size_t)b * TDEC + t) * TE + i] = awt;
    }
  }
}

// ---------------- main persistent kernel -------------------------------------
__global__ __launch_bounds__(256, 2) void k_main(Args A){
  const int blk = blockIdx.x, tid = threadIdx.x;
  int bt = 0;
  #pragma unroll 1
  for (int t = 0; t <= TDEC; ++t){
    // Phase 1: gate GEMMs + fused pointwise (all 256 blocks)
    if (t < TDEC) gemm_unit(A, 0, t, blk, tid);
    if (t >= 1)   gemm_unit(A, 1, t, blk, tid);
    gbar(A, ++bt);
    // Phase 2: loc (0..127), proj t-1 (128..139), pq (144..151), zeroing (152)
    if (blk < 128){ if (t < TDEC) loc_unit(A, t, blk, tid); }
    else if (blk < 140){ if (t >= 1) proj_unit(A, t, blk - 128, tid); }
    else if (blk >= 144 && blk < 152){ if (t < TDEC) pq_unit(A, t, blk - 144, tid); }
    else if (blk == 152){
      if (tid < 128) A.pw_flag[tid] = 0;
      else if (tid < 192) A.expsum[tid - 128] = 0.f;
      else A.done[tid - 192] = 0;
    }
    gbar(A, ++bt);
    // Phase 3: attention e/softmax/ctx
    if (t < TDEC) attn_unit(A, t, blk, tid);
    gbar(A, ++bt);
  }
}

// ---------------- setup kernels ----------------------------------------------
__global__ void k_prenet1(Args A){
  __shared__ float din[8 * 80];
  int g0 = blockIdx.x * 8;
  for (int idx = threadIdx.x; idx < 640; idx += 256){
    int r = idx / 80, k = idx % 80;
    int row = g0 + r;
    int t = row >> 6, b = row & 63;
    din[idx] = (t == 0) ? 0.f : A.dec_in[((size_t)(t - 1) * NBATCH + b) * NMEL + k];
  }
  __syncthreads();
  int j = threadIdx.x;
  float acc[8] = {0,0,0,0,0,0,0,0};
  for (int k = 0; k < 80; ++k){
    float w = A.W1[(size_t)j * 80 + k];
    #pragma unroll
    for (int r = 0; r < 8; ++r) acc[r] += w * din[r * 80 + k];
  }
  float bb = A.b1[j];
  #pragma unroll
  for (int r = 0; r < 8; ++r){
    float vx = acc[r] + bb; if (vx < 0.f) vx = 0.f;
    A.hid_bf[(size_t)(g0 + r) * PRE + j] = f2b(vx);
  }
}

__global__ void k_prenet2(Args A){
  __shared__ float hrow[8 * 256];
  int g0 = blockIdx.x * 8;
  for (int idx = threadIdx.x; idx < 2048; idx += 256){
    int r = idx >> 8, k = idx & 255;
    hrow[idx] = b2f(A.hid_bf[(size_t)(g0 + r) * PRE + k]);
  }
  __syncthreads();
  int j = threadIdx.x;
  float acc[8] = {0,0,0,0,0,0,0,0};
  for (int k = 0; k < 256; ++k){
    float w = A.W2[(size_t)j * PRE + k];
    #pragma unroll
    for (int r = 0; r < 8; ++r) acc[r] += w * hrow[r * 256 + k];
  }
  float bb = A.b2[j];
  #pragma unroll
  for (int r = 0; r < 8; ++r){
    float vx = acc[r] + bb; if (vx < 0.f) vx = 0.f;
    A.x_all[(size_t)(g0 + r) * PRE + j] = f2b(vx);
  }
}

__global__ void k_membf(Args A){
  size_t n = (size_t)NBATCH * TE * ED;
  for (size_t i = (size_t)blockIdx.x * 256 + threadIdx.x; i < n; i += (size_t)gridDim.x * 256)
    A.mem_bf[i] = f2b(A.mem[i]);
}

__global__ void k_pmem(Args A){
  __shared__ float mrow[8 * 512];
  int g0 = blockIdx.x * 8;   // rows = b*512 + t
  for (int idx = threadIdx.x; idx < 4096; idx += 256){
    int r = idx >> 9, k = idx & 511;
    mrow[idx] = A.mem[(size_t)(g0 + r) * ED + k];
  }
  __syncthreads();
  int d = threadIdx.x & 127, hh = threadIdx.x >> 7;
  float acc[4] = {0,0,0,0};
  for (int k = 0; k < 512; ++k){
    float w = A.Wm[(size_t)d * ED + k];
    #pragma unroll
    for (int r = 0; r < 4; ++r) acc[r] += w * mrow[(hh * 4 + r) * 512 + k];
  }
  #pragma unroll
  for (int r = 0; r < 4; ++r)
    A.pmem_bf[(size_t)(g0 + hh * 4 + r) * AD + d] = f2b(acc[r]);
}

// swizzle all B operands into MFMA fragment-linear layout:
// element (nt,kt,lane,j) <- B[k=kt*32+(lane>>4)*8+j][n=nt*16+(lane&15)]
__global__ void k_swz(Args A){
  const size_t Na = 917504, Nd = 1310720, Nq = 16384, Npg = 18432, Nu2 = 1024;
  const size_t NT = Na + Nd + Nq + Npg + Nu2;
  size_t id = (size_t)blockIdx.x * 256 + threadIdx.x;
  if (id >= NT + 8288) return;
  if (id < NT){
    int which; size_t lid; int NKT; u16* dst;
    if (id < Na){ which = 0; lid = id; NKT = 56; dst = A.WaSwz; }
    else if (id < Na + Nd){ which = 1; lid = id - Na; NKT = 80; dst = A.WdSwz; }
    else if (id < Na + Nd + Nq){ which = 2; lid = id - Na - Nd; NKT = 32; dst = A.WqSwz; }
    else if (id < Na + Nd + Nq + Npg){ which = 3; lid = id - Na - Nd - Nq; NKT = 48; dst = A.WpgSwz; }
    else { which = 4; lid = id - Na - Nd - Nq - Npg; NKT = 2; dst = A.U2Swz; }
    int lane = lid & 63;
    size_t rem = lid >> 6;
    int kt = (int)(rem % NKT), nt = (int)(rem / NKT);
    int n = (nt << 4) + (lane & 15);
    int k0 = (kt << 5) + ((lane >> 4) << 3);
    union { u16 h[8]; uint4 u; } o;
    #pragma unroll
    for (int j = 0; j < 8; ++j){
      int k = k0 + j;
      float vv = 0.f;
      if (which == 0){
        int rr = (n & 3) * 1024 + (n >> 2);
        vv = (k < 768) ? A.Wi_a[(size_t)rr * 768 + k] : A.Wh_a[(size_t)rr * 1024 + (k - 768)];
      } else if (which == 1){
        int rr = (n & 3) * 1024 + (n >> 2);
        vv = (k < 1536) ? A.Wi_d[(size_t)rr * 1536 + k] : A.Wh_d[(size_t)rr * 1024 + (k - 1536)];
      } else if (which == 2){
        vv = A.Wq[(size_t)n * 1024 + k];
      } else if (which == 3){
        vv = (n < 80) ? A.Wp[(size_t)n * 1536 + k] : ((n == 80) ? A.Wg[k] : 0.f);
      } else {
        int c = k >> 5, kk = k & 31;
        if (kk < 31){
          float s = 0.f;
          for (int f = 0; f < 32; ++f)
            s += A.Wld[(size_t)n * 32 + f] * A.Wloc[(size_t)(f * 2 + c) * 31 + kk];
          vv = s;
        }
      }
      o.h[j] = f2b(vv);
    }
    *(uint4*)(dst + lid * 8) = o.u;
  } else {
    size_t bid = id - NT;
    if (bid < 4096){
      int rr = ((int)bid & 3) * 1024 + ((int)bid >> 2);
      A.bias_a[bid] = A.bi_a[rr] + A.bh_a[rr];
    } else if (bid < 8192){
      int n = (int)bid - 4096;
      int rr = (n & 3) * 1024 + (n >> 2);
      A.bias_d[n] = A.bi_d[rr] + A.bh_d[rr];
    } else {
      int n = (int)bid - 8192;
      A.bpg[n] = (n < 80) ? A.bp[n] : ((n == 80) ? A.bg[0] : 0.f);
    }
  }
}

// ---------------- launcher ---------------------------------------------------
extern "C" void kernel_launch(void* const* d_in, const int* in_sizes, int n_in,
                              void* d_out, int out_size, void* d_ws, size_t ws_size,
                              hipStream_t stream){
  Args A;
  A.mem   = (const float*)d_in[0];
  A.dec_in= (const float*)d_in[1];
  A.mlen  = (const int*)d_in[2];
  A.W1 = (const float*)d_in[3];  A.b1 = (const float*)d_in[4];
  A.W2 = (const float*)d_in[5];  A.b2 = (const float*)d_in[6];
  A.Wi_a = (const float*)d_in[7];  A.Wh_a = (const float*)d_in[8];
  A.bi_a = (const float*)d_in[9];  A.bh_a = (const float*)d_in[10];
  A.Wq = (const float*)d_in[11]; A.Wm = (const float*)d_in[12];
  A.v_in = (const float*)d_in[13];
  A.Wloc = (const float*)d_in[14]; A.Wld = (const float*)d_in[15];
  A.Wi_d = (const float*)d_in[16]; A.Wh_d = (const float*)d_in[17];
  A.bi_d = (const float*)d_in[18]; A.bh_d = (const float*)d_in[19];
  A.Wp = (const float*)d_in[20]; A.bp = (const float*)d_in[21];
  A.Wg = (const float*)d_in[22]; A.bg = (const float*)d_in[23];

  uint8_t* w = (uint8_t*)d_ws;
  size_t cur = 0;
  auto AL = [&](size_t bytes) -> uint8_t* {
    uint8_t* p = w + cur;
    cur = (cur + bytes + 255) & ~(size_t)255;
    return p;
  };
  int* ctrl = (int*)AL(256); A.cnt = ctrl; A.gen = ctrl + 1;
  A.pw_flag = (int*)AL(128 * 4);
  A.expsum  = (float*)AL(64 * 4);
  A.done    = (int*)AL(64 * 4);
  A.ah_bf = (u16*)AL((size_t)2 * 64 * 1024 * 2);
  A.hc    = (u16*)AL((size_t)2 * 64 * 1536 * 2);
  A.ac = (float*)AL((size_t)64 * 1024 * 4);
  A.dc = (float*)AL((size_t)64 * 1024 * 4);
  A.aw  = (float*)AL((size_t)64 * 512 * 4);
  A.awc = (float*)AL((size_t)64 * 512 * 4);
  size_t zbytes = cur;   // everything above is zero-initialized per launch
  A.x_all   = (u16*)AL((size_t)TDEC * 64 * 256 * 2);
  A.pmem_bf = (u16*)AL((size_t)64 * 512 * 128 * 2);
  A.WaSwz  = (u16*)AL((size_t)1792 * 4096 * 2);
  A.WdSwz  = (u16*)AL((size_t)2560 * 4096 * 2);
  A.WqSwz  = (u16*)AL((size_t)1024 * 128 * 2);
  A.WpgSwz = (u16*)AL((size_t)1536 * 96 * 2);
  A.U2Swz  = (u16*)AL((size_t)64 * 128 * 2);
  A.bias_a = (float*)AL(4096 * 4);
  A.bias_d = (float*)AL(4096 * 4);
  A.bpg    = (float*)AL(96 * 4);
  A.pq     = (float*)AL((size_t)64 * 128 * 4);
  A.exp_e  = (float*)AL((size_t)64 * 512 * 4);
  A.loc_bf = (u16*)AL((size_t)64 * 512 * 128 * 2);
  A.gates_part = (float*)AL((size_t)2 * 4 * 64 * 4096 * 4);
  A.mem_bf = (u16*)AL((size_t)64 * 512 * 512 * 2);
  A.hid_bf = A.mem_bf;   // prenet temp aliases mem_bf (prenet runs before k_membf)

  float* out = (float*)d_out;
  A.out_mel  = out;
  A.out_gate = out + (size_t)64 * 800 * 80;
  A.out_align= A.out_gate + (size_t)64 * 800;

  hipMemsetAsync(d_ws, 0, zbytes, stream);
  hipMemsetAsync(d_out, 0, ((size_t)64 * 800 * 80 + 64 * 800) * 4, stream);  // mel+gate accumulated atomically
  k_prenet1<<<dim3(6400), dim3(256), 0, stream>>>(A);
  k_prenet2<<<dim3(6400), dim3(256), 0, stream>>>(A);
  k_membf<<<dim3(4096), dim3(256), 0, stream>>>(A);
  k_pmem<<<dim3(4096), dim3(256), 0, stream>>>(A);
  k_swz<<<dim3(8877), dim3(256), 0, stream>>>(A);
  k_main<<<dim3(256), dim3(256), 0, stream>>>(A);
}

// Round 2
// 72764.941 us; speedup vs baseline: 3.6988x; 3.6988x over previous
//
#include <hip/hip_runtime.h>
#include <stdint.h>

#define TDEC 800
#define NBATCH 64
#define TE 512
#define ED 512
#define NMEL 80
#define PRE 256
#define AR 1024
#define AD 128

typedef unsigned short u16;
typedef __bf16 bf16x8 __attribute__((ext_vector_type(8)));
typedef float f32x4 __attribute__((ext_vector_type(4)));

struct Args {
  // inputs
  const float *mem, *dec_in; const int *mlen;
  const float *W1, *b1, *W2, *b2;
  const float *Wi_a, *Wh_a, *bi_a, *bh_a;
  const float *Wq, *Wm, *v_in, *Wloc, *Wld;
  const float *Wi_d, *Wh_d, *bi_d, *bh_d;
  const float *Wp, *bp, *Wg, *bg;
  // control (all cacheline-padded where polled)
  int *grp_cnt, *root_cnt, *gen_root, *gen_grp, *pq_flag, *pw_flag, *done_pad;
  float *expsum_pad;
  // state
  u16 *ah_bf, *hc; float *ac, *dc, *aw, *awc;
  // staged data
  u16 *x_all, *pmem_bf, *mem_bf, *hid_bf;
  u16 *WaSwz, *WdSwz, *WqSwz, *WpgSwz, *U2Swz;
  float *bias_a, *bias_d, *bpg;
  float *pq, *exp_e; float *gates_part;
  // outputs
  float *out_mel, *out_gate, *out_align;
};

__device__ __forceinline__ float b2f(u16 h){ return __uint_as_float(((uint32_t)h) << 16); }
__device__ __forceinline__ u16 f2b(float f){
  uint32_t u = __float_as_uint(f);
  uint32_t r = (u + 0x7fffu + ((u >> 16) & 1u)) >> 16;
  return (u16)r;
}
__device__ __forceinline__ float sigm(float x){ return 1.f / (1.f + __expf(-x)); }
__device__ __forceinline__ float tanh_(float x){ float e = __expf(2.f*x); return 1.f - 2.f/(e + 1.f); }

__device__ __forceinline__ f32x4 mfma16(bf16x8 a, bf16x8 b, f32x4 c){
  return __builtin_amdgcn_mfma_f32_16x16x32_bf16(a, b, c, 0, 0, 0);
}
__device__ __forceinline__ bf16x8 ldf(const u16* p){ return *(const bf16x8*)p; }

// ---------------- hierarchical grid barrier: relaxed polls, one inv/wb -------
__device__ void gbar(const Args& A, int blk, int tid, int bt){
  __syncthreads();               // compiler drains vmcnt before s_barrier
  if (tid == 0){
    __builtin_amdgcn_fence(__ATOMIC_RELEASE, "agent");   // wb dirty L2 once
    int g = blk >> 5;
    int old = __hip_atomic_fetch_add(&A.grp_cnt[g*16], 1, __ATOMIC_RELAXED, __HIP_MEMORY_SCOPE_AGENT);
    if (old == bt*32 - 1){
      int ro = __hip_atomic_fetch_add(&A.root_cnt[0], 1, __ATOMIC_RELAXED, __HIP_MEMORY_SCOPE_AGENT);
      if (ro == bt*8 - 1){
        __hip_atomic_store(&A.gen_root[0], bt, __ATOMIC_RELAXED, __HIP_MEMORY_SCOPE_AGENT);
      } else {
        while (__hip_atomic_load(&A.gen_root[0], __ATOMIC_RELAXED, __HIP_MEMORY_SCOPE_AGENT) < bt)
          __builtin_amdgcn_s_sleep(2);
      }
      __hip_atomic_store(&A.gen_grp[g*16], bt, __ATOMIC_RELAXED, __HIP_MEMORY_SCOPE_AGENT);
    } else {
      while (__hip_atomic_load(&A.gen_grp[g*16], __ATOMIC_RELAXED, __HIP_MEMORY_SCOPE_AGENT) < bt)
        __builtin_amdgcn_s_sleep(4);
    }
    __builtin_amdgcn_fence(__ATOMIC_ACQUIRE, "agent");   // inv once
  }
  __syncthreads();
}

// ---------------- Phase 1: gate GEMM, B from LDS, split-K x4 + fused LSTM ----
template<int WHICH, int KT>
__device__ __forceinline__ void gemm_unit(const Args& A, int t, int blk, int tid,
                                          const u16* sB, int* s_last){
  const int pc = t & 1, pp = (t + 1) & 1;
  const int nc = blk >> 2, kq = blk & 3;
  const int wave = tid >> 6, lane = tid & 63;
  const int mh = wave >> 1, nh = wave & 1;
  const int kg = (lane >> 4) << 3;
  const u16* ah_p  = A.ah_bf + (size_t)pp * NBATCH * AR;
  const u16* hc_pp = A.hc + (size_t)pp * NBATCH * 1536;
  const u16* hc_pc = A.hc + (size_t)pc * NBATCH * 1536;
  const int row0 = mh*32 + (lane & 15);
  const int row1 = row0 + 16;
  const u16 *b0a, *b1a, *b2a, *b0b, *b1b, *b2b;
  if (WHICH == 0){
    b0a = A.x_all + ((size_t)t*NBATCH + row0)*PRE;
    b1a = hc_pp + (size_t)row0*1536 + (1024 - 256);
    b2a = ah_p + (size_t)row0*AR - 768;
    b0b = A.x_all + ((size_t)t*NBATCH + row1)*PRE;
    b1b = hc_pp + (size_t)row1*1536 + (1024 - 256);
    b2b = ah_p + (size_t)row1*AR - 768;
  } else {
    b0a = ah_p + (size_t)row0*AR;
    b1a = hc_pp + (size_t)row0*1536;          // +k gives ctx cols (k in [1024,1536))
    b2a = hc_pc + (size_t)row0*1536 - 1536;
    b0b = ah_p + (size_t)row1*AR;
    b1b = hc_pp + (size_t)row1*1536;
    b2b = hc_pc + (size_t)row1*1536 - 1536;
  }
  const int S0 = WHICH ? 1024 : 256;
  const int S1 = WHICH ? 1536 : 768;
  f32x4 acc00 = {0.f,0.f,0.f,0.f}, acc01 = acc00, acc10 = acc00, acc11 = acc00;
  const int kbase = kq*KT*32 + kg;
  #pragma unroll
  for (int kk = 0; kk < KT; ++kk){
    int k = kbase + kk*32;
    const u16* apa = (k < S0 ? b0a : (k < S1 ? b1a : b2a)) + k;
    const u16* apb = (k < S0 ? b0b : (k < S1 ? b1b : b2b)) + k;
    bf16x8 a0 = ldf(apa), a1 = ldf(apb);
    const u16* bb = sB + ((size_t)(2*nh)*KT + kk)*512 + lane*8;
    bf16x8 w0 = *(const bf16x8*)bb;
    bf16x8 w1 = *(const bf16x8*)(bb + (size_t)KT*512);
    acc00 = mfma16(a0, w0, acc00); acc01 = mfma16(a0, w1, acc01);
    acc10 = mfma16(a1, w0, acc10); acc11 = mfma16(a1, w1, acc11);
  }
  float* gp = A.gates_part + (size_t)(WHICH*4 + kq)*NBATCH*4096;
  int rr0 = mh*32 + ((lane>>4)<<2);
  int c0 = nc*64 + nh*32 + (lane & 15);
  #pragma unroll
  for (int r = 0; r < 4; ++r){
    gp[(size_t)(rr0+r)*4096 + c0     ] = acc00[r];
    gp[(size_t)(rr0+r)*4096 + c0 + 16] = acc01[r];
    gp[(size_t)(rr0+16+r)*4096 + c0     ] = acc10[r];
    gp[(size_t)(rr0+16+r)*4096 + c0 + 16] = acc11[r];
  }
  __syncthreads();               // drains all waves' stores (vmcnt0 before s_barrier)
  if (tid == 0){
    int old = __hip_atomic_fetch_add(&A.pw_flag[WHICH*64 + nc], 1,
                                     __ATOMIC_ACQ_REL, __HIP_MEMORY_SCOPE_AGENT);
    *s_last = (old == 3) ? 1 : 0;
  }
  __syncthreads();
  if (*s_last){
    const float* bias = WHICH ? A.bias_d : A.bias_a;
    float* cst = WHICH ? A.dc : A.ac;
    u16* hout = WHICH ? (A.hc + (size_t)pp * NBATCH * 1536)
                      : (A.ah_bf + (size_t)pc * NBATCH * AR);
    int hstride = WHICH ? 1536 : 1024;
    const float* g0 = A.gates_part + (size_t)WHICH*4*NBATCH*4096;
    #pragma unroll
    for (int cell = tid; cell < 1024; cell += 256){
      int bb2 = cell >> 4, jj = cell & 15;
      int col = nc*64 + jj*4;
      size_t base = (size_t)bb2 * 4096 + col;
      float gi = 0.f, gf = 0.f, gg = 0.f, go = 0.f;
      #pragma unroll
      for (int q = 0; q < 4; ++q){
        const float* gq = g0 + (size_t)q * NBATCH * 4096 + base;
        gi += gq[0]; gf += gq[1]; gg += gq[2]; go += gq[3];
      }
      gi += bias[col]; gf += bias[col+1]; gg += bias[col+2]; go += bias[col+3];
      int j = nc*16 + jj;
      size_t ci = (size_t)bb2 * AR + j;
      float cold = cst[ci];
      float cn = sigm(gf) * cold + sigm(gi) * tanh_(gg);
      cst[ci] = cn;
      float h = sigm(go) * tanh_(cn);
      hout[(size_t)bb2 * hstride + j] = f2b(h);
    }
  }
}

// ---------------- P3 pieces --------------------------------------------------
__device__ __forceinline__ void loc_chunk(const Args& A, int b, int tb, int tid,
                                          u16* sLoc, const bf16x8* U2reg){
  int wave = tid >> 6, lane = tid & 63;
  int tg0 = tb + wave*16 + (lane & 15);
  int kk0 = (lane >> 4) << 3;
  f32x4 acc[8];
  #pragma unroll
  for (int nt = 0; nt < 8; ++nt) acc[nt] = f32x4{0.f,0.f,0.f,0.f};
  #pragma unroll
  for (int kt = 0; kt < 2; ++kt){
    const float* src = (kt ? A.awc : A.aw) + (size_t)b*TE;
    int base = tg0 - 15 + kk0;
    union { u16 h[8]; bf16x8 v; } af;
    #pragma unroll
    for (int j = 0; j < 8; ++j){
      int idx = base + j;
      float f = (idx >= 0 && idx < TE) ? src[idx] : 0.f;
      af.h[j] = f2b(f);
    }
    #pragma unroll
    for (int nt = 0; nt < 8; ++nt) acc[nt] = mfma16(af.v, U2reg[kt*8 + nt], acc[nt]);
  }
  int rrow = wave*16 + ((lane>>4)<<2);
  #pragma unroll
  for (int nt = 0; nt < 8; ++nt){
    int d = nt*16 + (lane & 15);
    #pragma unroll
    for (int r = 0; r < 4; ++r) sLoc[(rrow + r)*136 + d] = f2b(acc[nt][r]);
  }
}

__device__ __forceinline__ float e_chunk(const Args& A, int b, int tb, int tid,
                                         const u16* sLoc, const float* s_pq,
                                         const float* s_v, int mlen){
  int tl = tid >> 2, h4 = tid & 3;
  int tg = tb + tl;
  int d0 = h4 * 32;
  const u16* prow = A.pmem_bf + ((size_t)b*TE + tg)*AD + d0;
  const u16* lrow = sLoc + tl*136 + d0;
  float s = 0.f;
  #pragma unroll
  for (int dq = 0; dq < 4; ++dq){
    bf16x8 pv = ldf(prow + dq*8);
    bf16x8 lv = *(const bf16x8*)(lrow + dq*8);
    #pragma unroll
    for (int j = 0; j < 8; ++j){
      int d = d0 + dq*8 + j;
      float arg = s_pq[d] + (float)lv[j] + (float)pv[j];
      s += tanh_(arg) * s_v[d];
    }
  }
  s += __shfl_xor(s, 1); s += __shfl_xor(s, 2);
  float ex = 0.f;
  if (h4 == 0 && tg < mlen) ex = __expf(s);
  if (h4 == 0) A.exp_e[(size_t)b*TE + tg] = ex;
  return ex;
}

__device__ __forceinline__ void ctx_unit(const Args& A, int t, int b, int c, int tid,
                                         float inv, float* s_ctx){
  int wave = tid >> 6, lane = tid & 63;
  int dseg = lane & 15;
  int rr = lane >> 4;
  const u16* mb = A.mem_bf + ((size_t)b*TE)*ED + c*128 + dseg*8;
  const float* ee = A.exp_e + (size_t)b*TE;
  float a[8] = {0.f,0.f,0.f,0.f,0.f,0.f,0.f,0.f};
  int tbase = wave * 128;
  #pragma unroll 8
  for (int i = 0; i < 32; ++i){
    int tt = tbase + i*4 + rr;
    float wt = ee[tt];
    bf16x8 mv = ldf(mb + (size_t)tt * ED);
    #pragma unroll
    for (int j = 0; j < 8; ++j) a[j] += wt * (float)mv[j];
  }
  #pragma unroll
  for (int j = 0; j < 8; ++j){ a[j] += __shfl_xor(a[j], 16); a[j] += __shfl_xor(a[j], 32); }
  if (lane < 16){
    #pragma unroll
    for (int j = 0; j < 8; ++j) s_ctx[wave*128 + dseg*8 + j] = a[j];
  }
  __syncthreads();
  if (tid < 128){
    float sum = (s_ctx[tid] + s_ctx[128+tid] + s_ctx[256+tid] + s_ctx[384+tid]) * inv;
    int pc = t & 1;
    A.hc[(size_t)pc*NBATCH*1536 + (size_t)b*1536 + 1024 + c*128 + tid] = f2b(sum);
  }
}

__device__ __forceinline__ void pq_unit(const Args& A, int t, int s, int tid){
  int pc = t & 1;
  int wave = tid >> 6, lane = tid & 63;
  int m = wave*16 + (lane & 15), kg = (lane >> 4) << 3;
  const u16* arow = A.ah_bf + (size_t)pc*NBATCH*AR + (size_t)m*AR + kg;
  f32x4 acc = {0.f,0.f,0.f,0.f};
  #pragma unroll 8
  for (int kt = 0; kt < 32; ++kt){
    bf16x8 af = ldf(arow + kt*32);
    bf16x8 bb = ldf(A.WqSwz + (((size_t)s*32 + kt)*64 + lane)*8);
    acc = mfma16(af, bb, acc);
  }
  int r0 = wave*16 + ((lane>>4)<<2);
  int d = s*16 + (lane & 15);
  #pragma unroll
  for (int r = 0; r < 4; ++r) A.pq[(size_t)(r0+r)*AD + d] = acc[r];
}

__device__ __forceinline__ void proj_unit(const Args& A, int t, int ns, int tid){
  int pp = (t + 1) & 1;
  int wave = tid >> 6, lane = tid & 63;
  int m = wave*16 + (lane & 15), kg = (lane >> 4) << 3;
  const u16* arow = A.hc + (size_t)pp*NBATCH*1536 + (size_t)m*1536 + kg;
  int n = ns*16 + (lane & 15);
  float bv = A.bpg[n];
  f32x4 acc = {bv, bv, bv, bv};
  #pragma unroll 8
  for (int kt = 0; kt < 48; ++kt){
    bf16x8 af = ldf(arow + kt*32);
    bf16x8 bb = ldf(A.WpgSwz + (((size_t)ns*48 + kt)*64 + lane)*8);
    acc = mfma16(af, bb, acc);
  }
  int r0 = wave*16 + ((lane>>4)<<2);
  #pragma unroll
  for (int r = 0; r < 4; ++r){
    int bb2 = r0 + r;
    if (n < 80)       A.out_mel[((size_t)bb2*TDEC + (t-1))*NMEL + n] = acc[r];
    else if (n == 80) A.out_gate[(size_t)bb2*TDEC + (t-1)] = acc[r];
  }
}

// ---------------- main persistent kernel -------------------------------------
__global__ __launch_bounds__(256, 1) void k_main(Args A){
  __shared__ u16 sW[69632];        // Wa slice 28672 u16 + Wd slice 40960 u16 = 136 KB
  __shared__ u16 sLoc[64*136];     // 17 KB, padded stride 136
  __shared__ float s_pq[128], s_v[128], s_ctx[512], s_red[4];
  __shared__ int s_last;
  const int blk = blockIdx.x, tid = threadIdx.x;
  const int nc = blk >> 2, kq = blk & 3;
  const int b = blk & 63, c = blk >> 6;
  // stage LSTM weight slices into LDS (persist for all 800 steps)
  #pragma unroll
  for (int ntl = 0; ntl < 4; ++ntl){
    const uint4* g = (const uint4*)(A.WaSwz + (((size_t)(4*nc + ntl)*56 + kq*14)*64)*8);
    uint4* l = (uint4*)(sW + (size_t)ntl*14*512);
    for (int i = tid; i < 14*64; i += 256) l[i] = g[i];
  }
  #pragma unroll
  for (int ntl = 0; ntl < 4; ++ntl){
    const uint4* g = (const uint4*)(A.WdSwz + (((size_t)(4*nc + ntl)*80 + kq*20)*64)*8);
    uint4* l = (uint4*)(sW + 28672 + (size_t)ntl*20*512);
    for (int i = tid; i < 20*64; i += 256) l[i] = g[i];
  }
  if (tid < 128) s_v[tid] = A.v_in[tid];
  bf16x8 U2reg[16];
  #pragma unroll
  for (int kt = 0; kt < 2; ++kt)
    #pragma unroll
    for (int nt = 0; nt < 8; ++nt)
      U2reg[kt*8 + nt] = ldf(A.U2Swz + ((size_t)((nt*2 + kt)*64 + (tid & 63)))*8);
  int mlen = A.mlen[b];
  __syncthreads();
  int bt = 0;
  #pragma unroll 1
  for (int t = 0; t <= TDEC; ++t){
    // ---- Phase 1: LSTM gate GEMMs + fused pointwise ----
    if (t < TDEC) gemm_unit<0,14>(A, t, blk, tid, sW, &s_last);
    if (t >= 1)   gemm_unit<1,20>(A, t, blk, tid, sW + 28672, &s_last);
    if (t < TDEC && blk == 255){
      if (tid < 64) A.expsum_pad[tid*16] = 0.f;
      else if (tid < 128) A.done_pad[(tid - 64)*16] = 0;
      else if (tid == 128) A.pq_flag[0] = 0;
    }
    gbar(A, blk, tid, ++bt);
    // ---- Phase 3: pq/proj duties + loc + e + softmax + ctx ----
    if (t < TDEC){
      if (blk >= 64 && blk < 72){
        pq_unit(A, t, blk - 64, tid);
        __syncthreads();
        if (tid == 0){
          __builtin_amdgcn_fence(__ATOMIC_RELEASE, "agent");
          __hip_atomic_fetch_add(&A.pq_flag[0], 1, __ATOMIC_RELAXED, __HIP_MEMORY_SCOPE_AGENT);
        }
      }
      if (t >= 1 && blk >= 72 && blk < 78) proj_unit(A, t, blk - 72, tid);
      if (blk == 78 && tid < 128) A.pw_flag[tid] = 0;
      int tb = c * 128;
      loc_chunk(A, b, tb, tid, sLoc, U2reg);
      __syncthreads();
      if (tid == 0){
        while (__hip_atomic_load(&A.pq_flag[0], __ATOMIC_RELAXED, __HIP_MEMORY_SCOPE_AGENT) < 8)
          __builtin_amdgcn_s_sleep(8);
        __builtin_amdgcn_fence(__ATOMIC_ACQUIRE, "agent");
      }
      __syncthreads();
      if (tid < 128) s_pq[tid] = A.pq[(size_t)b*AD + tid];
      __syncthreads();
      float ws = e_chunk(A, b, tb, tid, sLoc, s_pq, s_v, mlen);
      __syncthreads();
      loc_chunk(A, b, tb + 64, tid, sLoc, U2reg);
      __syncthreads();
      ws += e_chunk(A, b, tb + 64, tid, sLoc, s_pq, s_v, mlen);
      #pragma unroll
      for (int o = 32; o >= 1; o >>= 1) ws += __shfl_xor(ws, o);
      if ((tid & 63) == 0) s_red[tid >> 6] = ws;
      __syncthreads();
      if (tid == 0){
        float tot = s_red[0] + s_red[1] + s_red[2] + s_red[3];
        __hip_atomic_fetch_add(&A.expsum_pad[b*16], tot, __ATOMIC_RELAXED, __HIP_MEMORY_SCOPE_AGENT);
        __builtin_amdgcn_fence(__ATOMIC_RELEASE, "agent");
        __hip_atomic_fetch_add(&A.done_pad[b*16], 1, __ATOMIC_RELAXED, __HIP_MEMORY_SCOPE_AGENT);
        while (__hip_atomic_load(&A.done_pad[b*16], __ATOMIC_RELAXED, __HIP_MEMORY_SCOPE_AGENT) < 4)
          __builtin_amdgcn_s_sleep(4);
        __builtin_amdgcn_fence(__ATOMIC_ACQUIRE, "agent");
      }
      __syncthreads();
      float inv = 1.f / A.expsum_pad[b*16];
      ctx_unit(A, t, b, c, tid, inv, s_ctx);
      if (c == 0){
        for (int i = tid; i < TE; i += 256){
          float awt = A.exp_e[(size_t)b*TE + i] * inv;
          A.aw[(size_t)b*TE + i] = awt;
          A.awc[(size_t)b*TE + i] += awt;
          A.out_align[((size_t)b*TDEC + t)*TE + i] = awt;
        }
      }
      gbar(A, blk, tid, ++bt);
    } else {
      if (blk >= 72 && blk < 78) proj_unit(A, t, blk - 72, tid);
    }
  }
}

// ---------------- setup kernels (unchanged from round 1) ---------------------
__global__ void k_prenet1(Args A){
  __shared__ float din[8 * 80];
  int g0 = blockIdx.x * 8;
  for (int idx = threadIdx.x; idx < 640; idx += 256){
    int r = idx / 80, k = idx % 80;
    int row = g0 + r;
    int t = row >> 6, b = row & 63;
    din[idx] = (t == 0) ? 0.f : A.dec_in[((size_t)(t - 1) * NBATCH + b) * NMEL + k];
  }
  __syncthreads();
  int j = threadIdx.x;
  float acc[8] = {0,0,0,0,0,0,0,0};
  for (int k = 0; k < 80; ++k){
    float w = A.W1[(size_t)j * 80 + k];
    #pragma unroll
    for (int r = 0; r < 8; ++r) acc[r] += w * din[r * 80 + k];
  }
  float bb = A.b1[j];
  #pragma unroll
  for (int r = 0; r < 8; ++r){
    float vx = acc[r] + bb; if (vx < 0.f) vx = 0.f;
    A.hid_bf[(size_t)(g0 + r) * PRE + j] = f2b(vx);
  }
}

__global__ void k_prenet2(Args A){
  __shared__ float hrow[8 * 256];
  int g0 = blockIdx.x * 8;
  for (int idx = threadIdx.x; idx < 2048; idx += 256){
    int r = idx >> 8, k = idx & 255;
    hrow[idx] = b2f(A.hid_bf[(size_t)(g0 + r) * PRE + k]);
  }
  __syncthreads();
  int j = threadIdx.x;
  float acc[8] = {0,0,0,0,0,0,0,0};
  for (int k = 0; k < 256; ++k){
    float w = A.W2[(size_t)j * PRE + k];
    #pragma unroll
    for (int r = 0; r < 8; ++r) acc[r] += w * hrow[r * 256 + k];
  }
  float bb = A.b2[j];
  #pragma unroll
  for (int r = 0; r < 8; ++r){
    float vx = acc[r] + bb; if (vx < 0.f) vx = 0.f;
    A.x_all[(size_t)(g0 + r) * PRE + j] = f2b(vx);
  }
}

__global__ void k_membf(Args A){
  size_t n = (size_t)NBATCH * TE * ED;
  for (size_t i = (size_t)blockIdx.x * 256 + threadIdx.x; i < n; i += (size_t)gridDim.x * 256)
    A.mem_bf[i] = f2b(A.mem[i]);
}

__global__ void k_pmem(Args A){
  __shared__ float mrow[8 * 512];
  int g0 = blockIdx.x * 8;
  for (int idx = threadIdx.x; idx < 4096; idx += 256){
    int r = idx >> 9, k = idx & 511;
    mrow[idx] = A.mem[(size_t)(g0 + r) * ED + k];
  }
  __syncthreads();
  int d = threadIdx.x & 127, hh = threadIdx.x >> 7;
  float acc[4] = {0,0,0,0};
  for (int k = 0; k < 512; ++k){
    float w = A.Wm[(size_t)d * ED + k];
    #pragma unroll
    for (int r = 0; r < 4; ++r) acc[r] += w * mrow[(hh * 4 + r) * 512 + k];
  }
  #pragma unroll
  for (int r = 0; r < 4; ++r)
    A.pmem_bf[(size_t)(g0 + hh * 4 + r) * AD + d] = f2b(acc[r]);
}

__global__ void k_swz(Args A){
  const size_t Na = 917504, Nd = 1310720, Nq = 16384, Npg = 18432, Nu2 = 1024;
  const size_t NT = Na + Nd + Nq + Npg + Nu2;
  size_t id = (size_t)blockIdx.x * 256 + threadIdx.x;
  if (id >= NT + 8288) return;
  if (id < NT){
    int which; size_t lid; int NKT; u16* dst;
    if (id < Na){ which = 0; lid = id; NKT = 56; dst = A.WaSwz; }
    else if (id < Na + Nd){ which = 1; lid = id - Na; NKT = 80; dst = A.WdSwz; }
    else if (id < Na + Nd + Nq){ which = 2; lid = id - Na - Nd; NKT = 32; dst = A.WqSwz; }
    else if (id < Na + Nd + Nq + Npg){ which = 3; lid = id - Na - Nd - Nq; NKT = 48; dst = A.WpgSwz; }
    else { which = 4; lid = id - Na - Nd - Nq - Npg; NKT = 2; dst = A.U2Swz; }
    int lane = lid & 63;
    size_t rem = lid >> 6;
    int kt = (int)(rem % NKT), nt = (int)(rem / NKT);
    int n = (nt << 4) + (lane & 15);
    int k0 = (kt << 5) + ((lane >> 4) << 3);
    union { u16 h[8]; uint4 u; } o;
    #pragma unroll
    for (int j = 0; j < 8; ++j){
      int k = k0 + j;
      float vv = 0.f;
      if (which == 0){
        int rr = (n & 3) * 1024 + (n >> 2);
        vv = (k < 768) ? A.Wi_a[(size_t)rr * 768 + k] : A.Wh_a[(size_t)rr * 1024 + (k - 768)];
      } else if (which == 1){
        int rr = (n & 3) * 1024 + (n >> 2);
        vv = (k < 1536) ? A.Wi_d[(size_t)rr * 1536 + k] : A.Wh_d[(size_t)rr * 1024 + (k - 1536)];
      } else if (which == 2){
        vv = A.Wq[(size_t)n * 1024 + k];
      } else if (which == 3){
        vv = (n < 80) ? A.Wp[(size_t)n * 1536 + k] : ((n == 80) ? A.Wg[k] : 0.f);
      } else {
        int cc = k >> 5, kk = k & 31;
        if (kk < 31){
          float s = 0.f;
          for (int f = 0; f < 32; ++f)
            s += A.Wld[(size_t)n * 32 + f] * A.Wloc[(size_t)(f * 2 + cc) * 31 + kk];
          vv = s;
        }
      }
      o.h[j] = f2b(vv);
    }
    *(uint4*)(dst + lid * 8) = o.u;
  } else {
    size_t bid = id - NT;
    if (bid < 4096){
      int rr = ((int)bid & 3) * 1024 + ((int)bid >> 2);
      A.bias_a[bid] = A.bi_a[rr] + A.bh_a[rr];
    } else if (bid < 8192){
      int n = (int)bid - 4096;
      int rr = (n & 3) * 1024 + (n >> 2);
      A.bias_d[n] = A.bi_d[rr] + A.bh_d[rr];
    } else {
      int n = (int)bid - 8192;
      A.bpg[n] = (n < 80) ? A.bp[n] : ((n == 80) ? A.bg[0] : 0.f);
    }
  }
}

// ---------------- launcher ---------------------------------------------------
extern "C" void kernel_launch(void* const* d_in, const int* in_sizes, int n_in,
                              void* d_out, int out_size, void* d_ws, size_t ws_size,
                              hipStream_t stream){
  Args A;
  A.mem   = (const float*)d_in[0];
  A.dec_in= (const float*)d_in[1];
  A.mlen  = (const int*)d_in[2];
  A.W1 = (const float*)d_in[3];  A.b1 = (const float*)d_in[4];
  A.W2 = (const float*)d_in[5];  A.b2 = (const float*)d_in[6];
  A.Wi_a = (const float*)d_in[7];  A.Wh_a = (const float*)d_in[8];
  A.bi_a = (const float*)d_in[9];  A.bh_a = (const float*)d_in[10];
  A.Wq = (const float*)d_in[11]; A.Wm = (const float*)d_in[12];
  A.v_in = (const float*)d_in[13];
  A.Wloc = (const float*)d_in[14]; A.Wld = (const float*)d_in[15];
  A.Wi_d = (const float*)d_in[16]; A.Wh_d = (const float*)d_in[17];
  A.bi_d = (const float*)d_in[18]; A.bh_d = (const float*)d_in[19];
  A.Wp = (const float*)d_in[20]; A.bp = (const float*)d_in[21];
  A.Wg = (const float*)d_in[22]; A.bg = (const float*)d_in[23];

  uint8_t* w = (uint8_t*)d_ws;
  size_t cur = 0;
  auto AL = [&](size_t bytes) -> uint8_t* {
    uint8_t* p = w + cur;
    cur = (cur + bytes + 255) & ~(size_t)255;
    return p;
  };
  A.grp_cnt  = (int*)AL(8 * 16 * 4);
  A.root_cnt = (int*)AL(16 * 4);
  A.gen_root = (int*)AL(16 * 4);
  A.gen_grp  = (int*)AL(8 * 16 * 4);
  A.pq_flag  = (int*)AL(16 * 4);
  A.pw_flag  = (int*)AL(128 * 4);
  A.done_pad = (int*)AL(64 * 16 * 4);
  A.expsum_pad = (float*)AL(64 * 16 * 4);
  A.ah_bf = (u16*)AL((size_t)2 * 64 * 1024 * 2);
  A.hc    = (u16*)AL((size_t)2 * 64 * 1536 * 2);
  A.ac = (float*)AL((size_t)64 * 1024 * 4);
  A.dc = (float*)AL((size_t)64 * 1024 * 4);
  A.aw  = (float*)AL((size_t)64 * 512 * 4);
  A.awc = (float*)AL((size_t)64 * 512 * 4);
  size_t zbytes = cur;   // zero-initialized every launch
  A.x_all   = (u16*)AL((size_t)TDEC * 64 * 256 * 2);
  A.pmem_bf = (u16*)AL((size_t)64 * 512 * 128 * 2);
  A.WaSwz  = (u16*)AL((size_t)1792 * 4096 * 2);
  A.WdSwz  = (u16*)AL((size_t)2560 * 4096 * 2);
  A.WqSwz  = (u16*)AL((size_t)1024 * 128 * 2);
  A.WpgSwz = (u16*)AL((size_t)1536 * 96 * 2);
  A.U2Swz  = (u16*)AL((size_t)64 * 128 * 2);
  A.bias_a = (float*)AL(4096 * 4);
  A.bias_d = (float*)AL(4096 * 4);
  A.bpg    = (float*)AL(96 * 4);
  A.pq     = (float*)AL((size_t)64 * 128 * 4);
  A.exp_e  = (float*)AL((size_t)64 * 512 * 4);
  A.gates_part = (float*)AL((size_t)2 * 4 * 64 * 4096 * 4);
  A.mem_bf = (u16*)AL((size_t)64 * 512 * 512 * 2);
  A.hid_bf = A.mem_bf;   // prenet temp aliases mem_bf (prenet runs before k_membf)

  float* out = (float*)d_out;
  A.out_mel  = out;
  A.out_gate = out + (size_t)64 * 800 * 80;
  A.out_align= A.out_gate + (size_t)64 * 800;

  hipMemsetAsync(d_ws, 0, zbytes, stream);
  k_prenet1<<<dim3(6400), dim3(256), 0, stream>>>(A);
  k_prenet2<<<dim3(6400), dim3(256), 0, stream>>>(A);
  k_membf<<<dim3(4096), dim3(256), 0, stream>>>(A);
  k_pmem<<<dim3(4096), dim3(256), 0, stream>>>(A);
  k_swz<<<dim3(8877), dim3(256), 0, stream>>>(A);
  k_main<<<dim3(256), dim3(256), 0, stream>>>(A);
}